// Round 3
// baseline (160.718 us; speedup 1.0000x reference)
//
#include <hip/hip_runtime.h>
#include <hip/hip_bf16.h>

typedef __attribute__((ext_vector_type(4))) float f32x4;
typedef __attribute__((ext_vector_type(4))) int   i32x4;
typedef __attribute__((ext_vector_type(8))) short s16x8;

#define NB 131072
#define ND 8
#define NH 128
#define BROWS 256   // rows per block
#define MT 4        // 16-row tiles per wave

#if __has_builtin(__builtin_amdgcn_exp2f)
#define EXP2F(x) __builtin_amdgcn_exp2f(x)
#define PRESCALE 1.4426950408889634f
#else
#define EXP2F(x) __expf(x)
#define PRESESCALE_FALLBACK
#define PRESCALE 1.0f
#endif

#if __has_builtin(__builtin_amdgcn_rcpf)
#define RCPF(x) __builtin_amdgcn_rcpf(x)
#else
#define RCPF(x) (1.0f / (x))
#endif

__device__ __forceinline__ unsigned short f2bf(float f){
  unsigned u = __float_as_uint(f);
  u += 0x7fffu + ((u >> 16) & 1u);   // RTNE
  return (unsigned short)(u >> 16);
}

// pack two f32 -> dword of 2 bf16 (truncation), single v_perm_b32
__device__ __forceinline__ unsigned pk2(float lo, float hi){
  return __builtin_amdgcn_perm(__float_as_uint(hi), __float_as_uint(lo), 0x07060302u);
}

// w2 [d][n][k] f32 -> bf16 chunks [d][kb=k/8][n][8]
__global__ __launch_bounds__(256) void cvt_w2_kernel(const float* __restrict__ src,
                                                     uint4* __restrict__ dst){
  int i = blockIdx.x * 256 + threadIdx.x;         // 16384 chunks
  int d = i >> 11, kb = (i >> 7) & 15, n = i & 127;
  const float* s = src + ((d * 128 + n) * 128 + kb * 8);
  float4 v0 = ((const float4*)s)[0];
  float4 v1 = ((const float4*)s)[1];
  uint4 o;
  o.x = (unsigned)f2bf(v0.x) | ((unsigned)f2bf(v0.y) << 16);
  o.y = (unsigned)f2bf(v0.z) | ((unsigned)f2bf(v0.w) << 16);
  o.z = (unsigned)f2bf(v1.x) | ((unsigned)f2bf(v1.y) << 16);
  o.w = (unsigned)f2bf(v1.z) | ((unsigned)f2bf(v1.w) << 16);
  dst[i] = o;
}

// emb_w [d][n] f32 -> embT [n][8] bf16 (RTNE)
__global__ void cvt_emb_kernel(const float* __restrict__ emb_w, uint4* __restrict__ dst){
  int n = threadIdx.x;  // 128
  unsigned e0 = f2bf(emb_w[0*NH + n]), e1 = f2bf(emb_w[1*NH + n]);
  unsigned e2 = f2bf(emb_w[2*NH + n]), e3 = f2bf(emb_w[3*NH + n]);
  unsigned e4 = f2bf(emb_w[4*NH + n]), e5 = f2bf(emb_w[5*NH + n]);
  unsigned e6 = f2bf(emb_w[6*NH + n]), e7 = f2bf(emb_w[7*NH + n]);
  uint4 v;
  v.x = e0 | (e1 << 16);  v.y = e2 | (e3 << 16);
  v.z = e4 | (e5 << 16);  v.w = e6 | (e7 << 16);
  dst[n] = v;
}

__global__ __launch_bounds__(256, 2) void cond_embed_kernel(
    const float* __restrict__ labels,
    const float* __restrict__ w1,
    const float* __restrict__ b1,
    const unsigned short* __restrict__ w2b,   // [d][kb][n][8] bf16
    const unsigned short* __restrict__ embT,  // [n][8] bf16
    const int* __restrict__ uncond_p,
    float* __restrict__ out)
{
  __shared__ __align__(16) unsigned short lds_w2[2][NH * NH];  // 64 KB double buffer
  __shared__ __align__(16) float lds_lab[ND * BROWS];          // 8 KB, [d][row]
  __shared__ __align__(16) float lds_w1[ND * NH];              // 4 KB (log2e-scaled)
  __shared__ __align__(16) float lds_b1[ND * NH];              // 4 KB (log2e-scaled)
  // total exactly 80 KB -> 2 blocks/CU

  const int tid  = threadIdx.x;
  const int wave = tid >> 6;
  const int lane = tid & 63;
  const int quad = lane >> 4;
  const int l16  = lane & 15;
  const int uncond = uncond_p[0];
  const int blockbase = blockIdx.x * BROWS;

  // labels -> LDS transposed [d][row]
  {
    const float4* src = (const float4*)(labels + blockbase * ND);
    #pragma unroll
    for (int c = 0; c < 2; ++c){
      int i = tid + c * 256;
      float4 v = src[i];
      int row = i >> 1, db = (i & 1) * 4;
      lds_lab[(db + 0) * BROWS + row] = v.x;
      lds_lab[(db + 1) * BROWS + row] = v.y;
      lds_lab[(db + 2) * BROWS + row] = v.z;
      lds_lab[(db + 3) * BROWS + row] = v.w;
    }
  }
  // w1/b1 pre-scaled
  {
    float4 a = ((const float4*)w1)[tid];
    float4 b = ((const float4*)b1)[tid];
    ((float4*)lds_w1)[tid] = (float4){a.x * PRESCALE, a.y * PRESCALE, a.z * PRESCALE, a.w * PRESCALE};
    ((float4*)lds_b1)[tid] = (float4){b.x * PRESCALE, b.y * PRESCALE, b.z * PRESCALE, b.w * PRESCALE};
  }

  auto stage = [&](int d, int buf){
    const unsigned short* g = w2b + d * (NH * NH);
    #pragma unroll
    for (int i = 0; i < 8; ++i){
      int idx = tid + i * 256;   // 16B chunks, 2048 total
      __builtin_amdgcn_global_load_lds(
          (const __attribute__((address_space(1))) void*)(g + idx * 8),
          (__attribute__((address_space(3))) void*)(&lds_w2[buf][idx * 8]),
          16, 0, 0);
    }
  };

  stage(0, 0);
  __syncthreads();   // drain stage(0) + label/w1/b1 staging

  f32x4 acc[MT][8];
  #pragma unroll
  for (int mt = 0; mt < MT; ++mt)
    #pragma unroll
    for (int nt = 0; nt < 8; ++nt)
      acc[mt][nt] = (f32x4){0.f, 0.f, 0.f, 0.f};

  const s16x8 bones = (s16x8)((short)0x3F80);   // bf16 1.0

  for (int d = 0; d < ND; ++d){
    const int buf = d & 1;
    if (d < ND - 1) stage(d + 1, buf ^ 1);

    // per-row label / drop
    float xs[MT];
    #pragma unroll
    for (int mt = 0; mt < MT; ++mt){
      float x = lds_lab[d * BROWS + wave * 64 + mt * 16 + l16];
      bool drop = (uncond != 0) || (x != x);
      xs[mt] = drop ? 0.f : x;
    }

    // A fragments: t-outer so w1/b1 b128 loads are shared across all 4 mt
    s16x8 af[MT][4];
    #pragma unroll
    for (int t = 0; t < 4; ++t){
      const float4* w1q = (const float4*)&lds_w1[d * NH + t * 32 + quad * 8];
      const float4* b1q = (const float4*)&lds_b1[d * NH + t * 32 + quad * 8];
      float4 wa = w1q[0], wb = w1q[1];
      float4 ba = b1q[0], bb = b1q[1];
      #pragma unroll
      for (int mt = 0; mt < MT; ++mt){
        float x = xs[mt];
        float e0 = EXP2F(fmaf(x, wa.x, ba.x));
        float e1 = EXP2F(fmaf(x, wa.y, ba.y));
        float e2 = EXP2F(fmaf(x, wa.z, ba.z));
        float e3 = EXP2F(fmaf(x, wa.w, ba.w));
        float e4 = EXP2F(fmaf(x, wb.x, bb.x));
        float e5 = EXP2F(fmaf(x, wb.y, bb.y));
        float e6 = EXP2F(fmaf(x, wb.z, bb.z));
        float e7 = EXP2F(fmaf(x, wb.w, bb.w));
        i32x4 ai;
        ai[0] = (int)pk2(e0, e1);
        ai[1] = (int)pk2(e2, e3);
        ai[2] = (int)pk2(e4, e5);
        ai[3] = (int)pk2(e6, e7);
        af[mt][t] = __builtin_bit_cast(s16x8, ai);
      }
    }

    // Z per row via ones-MFMA (sum of quantized e -> truncation cancels)
    f32x4 zr[MT];
    #pragma unroll
    for (int mt = 0; mt < MT; ++mt){
      f32x4 z = (f32x4){0.f, 0.f, 0.f, 0.f};
      #pragma unroll
      for (int t = 0; t < 4; ++t)
        z = __builtin_amdgcn_mfma_f32_16x16x32_bf16(af[mt][t], bones, z, 0, 0, 0);
      float4 xc = *(const float4*)&lds_lab[d * BROWS + wave * 64 + mt * 16 + quad * 4];
      zr[mt][0] = ((uncond != 0) || (xc.x != xc.x)) ? 0.f : RCPF(z[0]);
      zr[mt][1] = ((uncond != 0) || (xc.y != xc.y)) ? 0.f : RCPF(z[1]);
      zr[mt][2] = ((uncond != 0) || (xc.z != xc.z)) ? 0.f : RCPF(z[2]);
      zr[mt][3] = ((uncond != 0) || (xc.w != xc.w)) ? 0.f : RCPF(z[3]);
    }

    // GEMM: each B fragment load feeds 4 MFMAs (mt amortization)
    #pragma unroll
    for (int nt = 0; nt < 8; ++nt){
      f32x4 tm[MT];
      #pragma unroll
      for (int mt = 0; mt < MT; ++mt) tm[mt] = (f32x4){0.f, 0.f, 0.f, 0.f};
      #pragma unroll
      for (int t = 0; t < 4; ++t){
        s16x8 b = *((const s16x8*)&lds_w2[buf][(t * 512 + quad * 128 + nt * 16 + l16) * 8]);
        #pragma unroll
        for (int mt = 0; mt < MT; ++mt)
          tm[mt] = __builtin_amdgcn_mfma_f32_16x16x32_bf16(af[mt][t], b, tm[mt], 0, 0, 0);
      }
      #pragma unroll
      for (int mt = 0; mt < MT; ++mt)
        #pragma unroll
        for (int r = 0; r < 4; ++r)
          acc[mt][nt][r] = fmaf(tm[mt][r], zr[mt][r], acc[mt][nt][r]);
    }

    if (d < ND - 1) __syncthreads();   // drains stage(d+1); protects buf reuse
  }

  // Embedding fallback: A_extra[m][k=d] = drop?1:0 (quad 0), B_extra[k=d][n] = emb_w[d][n]
  s16x8 aex[MT];
  #pragma unroll
  for (int mt = 0; mt < MT; ++mt){
    s16x8 a = (s16x8)((short)0);
    if (quad == 0){
      int row = wave * 64 + mt * 16 + l16;
      #pragma unroll
      for (int j = 0; j < 8; ++j){
        float x = lds_lab[j * BROWS + row];
        bool drop = (uncond != 0) || (x != x);
        a[j] = drop ? (short)0x3F80 : (short)0;
      }
    }
    aex[mt] = a;
  }
  #pragma unroll
  for (int nt = 0; nt < 8; ++nt){
    s16x8 b = (s16x8)((short)0);
    if (quad == 0) b = __builtin_bit_cast(s16x8, ((const i32x4*)embT)[nt * 16 + l16]);
    #pragma unroll
    for (int mt = 0; mt < MT; ++mt)
      acc[mt][nt] = __builtin_amdgcn_mfma_f32_16x16x32_bf16(aex[mt], b, acc[mt][nt], 0, 0, 0);
  }

  // store: C layout col = l16, row = quad*4 + r
  #pragma unroll
  for (int mt = 0; mt < MT; ++mt){
    #pragma unroll
    for (int nt = 0; nt < 8; ++nt){
      #pragma unroll
      for (int r = 0; r < 4; ++r){
        int row = blockbase + wave * 64 + mt * 16 + quad * 4 + r;
        out[row * NH + nt * 16 + l16] = acc[mt][nt][r];
      }
    }
  }
}

extern "C" void kernel_launch(void* const* d_in, const int* in_sizes, int n_in,
                              void* d_out, int out_size, void* d_ws, size_t ws_size,
                              hipStream_t stream){
  const float* labels = (const float*)d_in[0];
  const float* emb_w  = (const float*)d_in[1];
  const float* w1     = (const float*)d_in[2];
  const float* b1     = (const float*)d_in[3];
  const float* w2     = (const float*)d_in[4];
  const int*   uncond = (const int*)d_in[6];
  (void)in_sizes; (void)n_in; (void)out_size; (void)ws_size;

  float* out = (float*)d_out;
  unsigned short* w2b  = (unsigned short*)d_ws;          // 256 KB bf16 w2
  unsigned short* embT = w2b + ND * NH * NH;             // +2 KB bf16 embT[n][8]

  cvt_w2_kernel<<<64, 256, 0, stream>>>(w2, (uint4*)w2b);
  cvt_emb_kernel<<<1, 128, 0, stream>>>(emb_w, (uint4*)embT);
  cond_embed_kernel<<<NB / BROWS, 256, 0, stream>>>(labels, w1, b1, w2b, embT, uncond, out);
}

// Round 4
// 136.760 us; speedup vs baseline: 1.1752x; 1.1752x over previous
//
#include <hip/hip_runtime.h>
#include <hip/hip_bf16.h>

typedef __attribute__((ext_vector_type(4))) float f32x4;
typedef __attribute__((ext_vector_type(4))) int   i32x4;
typedef __attribute__((ext_vector_type(8))) short s16x8;

#define NB 131072
#define ND 8
#define NH 128
#define BROWS 128   // rows per block
#define MT 2        // 16-row tiles per wave (register-lean: no spills)

#if __has_builtin(__builtin_amdgcn_exp2f)
#define EXP2F(x) __builtin_amdgcn_exp2f(x)
#define PRESCALE 1.4426950408889634f
#else
#define EXP2F(x) __expf(x)
#define PRESCALE 1.0f
#endif

#if __has_builtin(__builtin_amdgcn_rcpf)
#define RCPF(x) __builtin_amdgcn_rcpf(x)
#else
#define RCPF(x) (1.0f / (x))
#endif

__device__ __forceinline__ unsigned short f2bf(float f){
  unsigned u = __float_as_uint(f);
  u += 0x7fffu + ((u >> 16) & 1u);   // RTNE
  return (unsigned short)(u >> 16);
}

// pack two f32 -> dword of 2 bf16 (truncation), single v_perm_b32
__device__ __forceinline__ unsigned pk2(float lo, float hi){
  return __builtin_amdgcn_perm(__float_as_uint(hi), __float_as_uint(lo), 0x07060302u);
}

// w2 [d][n][k] f32 -> bf16 chunks [d][kb=k/8][n][8]
__global__ __launch_bounds__(256) void cvt_w2_kernel(const float* __restrict__ src,
                                                     uint4* __restrict__ dst){
  int i = blockIdx.x * 256 + threadIdx.x;         // 16384 chunks
  int d = i >> 11, kb = (i >> 7) & 15, n = i & 127;
  const float* s = src + ((d * 128 + n) * 128 + kb * 8);
  float4 v0 = ((const float4*)s)[0];
  float4 v1 = ((const float4*)s)[1];
  uint4 o;
  o.x = (unsigned)f2bf(v0.x) | ((unsigned)f2bf(v0.y) << 16);
  o.y = (unsigned)f2bf(v0.z) | ((unsigned)f2bf(v0.w) << 16);
  o.z = (unsigned)f2bf(v1.x) | ((unsigned)f2bf(v1.y) << 16);
  o.w = (unsigned)f2bf(v1.z) | ((unsigned)f2bf(v1.w) << 16);
  dst[i] = o;
}

// emb_w [d][n] f32 -> embT [n][8] bf16 (RTNE)
__global__ void cvt_emb_kernel(const float* __restrict__ emb_w, uint4* __restrict__ dst){
  int n = threadIdx.x;  // 128
  unsigned e0 = f2bf(emb_w[0*NH + n]), e1 = f2bf(emb_w[1*NH + n]);
  unsigned e2 = f2bf(emb_w[2*NH + n]), e3 = f2bf(emb_w[3*NH + n]);
  unsigned e4 = f2bf(emb_w[4*NH + n]), e5 = f2bf(emb_w[5*NH + n]);
  unsigned e6 = f2bf(emb_w[6*NH + n]), e7 = f2bf(emb_w[7*NH + n]);
  uint4 v;
  v.x = e0 | (e1 << 16);  v.y = e2 | (e3 << 16);
  v.z = e4 | (e5 << 16);  v.w = e6 | (e7 << 16);
  dst[n] = v;
}

__global__ __launch_bounds__(256, 3) void cond_embed_kernel(
    const float* __restrict__ labels,
    const float* __restrict__ w1,
    const float* __restrict__ b1,
    const unsigned short* __restrict__ w2b,   // [d][kb][n][8] bf16
    const unsigned short* __restrict__ embT,  // [n][8] bf16
    const int* __restrict__ uncond_p,
    float* __restrict__ out)
{
  __shared__ __align__(16) unsigned short lds_w2[NH * NH];   // 32 KB single buffer
  __shared__ __align__(16) float lds_lab[ND * BROWS];        // 4 KB, [d][row]
  __shared__ __align__(16) float lds_w1[ND * NH];            // 4 KB (log2e-scaled)
  __shared__ __align__(16) float lds_b1[ND * NH];            // 4 KB (log2e-scaled)
  // 44 KB total -> 3 blocks/CU

  const int tid  = threadIdx.x;
  const int wave = tid >> 6;
  const int lane = tid & 63;
  const int quad = lane >> 4;
  const int l16  = lane & 15;
  const int uncond = uncond_p[0];
  const int blockbase = blockIdx.x * BROWS;

  // labels -> LDS transposed [d][row]
  {
    float4 v = ((const float4*)(labels + blockbase * ND))[tid];
    int row = tid >> 1, db = (tid & 1) * 4;
    lds_lab[(db + 0) * BROWS + row] = v.x;
    lds_lab[(db + 1) * BROWS + row] = v.y;
    lds_lab[(db + 2) * BROWS + row] = v.z;
    lds_lab[(db + 3) * BROWS + row] = v.w;
  }
  // w1/b1 pre-scaled by log2e
  {
    float4 a = ((const float4*)w1)[tid];
    float4 b = ((const float4*)b1)[tid];
    ((float4*)lds_w1)[tid] = (float4){a.x * PRESCALE, a.y * PRESCALE, a.z * PRESCALE, a.w * PRESCALE};
    ((float4*)lds_b1)[tid] = (float4){b.x * PRESCALE, b.y * PRESCALE, b.z * PRESCALE, b.w * PRESCALE};
  }

  f32x4 acc[MT][8];
  #pragma unroll
  for (int mt = 0; mt < MT; ++mt)
    #pragma unroll
    for (int nt = 0; nt < 8; ++nt)
      acc[mt][nt] = (f32x4){0.f, 0.f, 0.f, 0.f};

  const s16x8 bones = (s16x8)((short)0x3F80);   // bf16 1.0

  for (int d = 0; d < ND; ++d){
    __syncthreads();   // previous tile fully consumed (covers initial staging at d=0)
    {
      const unsigned short* g = w2b + d * (NH * NH);
      #pragma unroll
      for (int i = 0; i < 8; ++i){
        int idx = tid + i * 256;   // 16B chunks, 2048 total = 32 KB
        __builtin_amdgcn_global_load_lds(
            (const __attribute__((address_space(1))) void*)(g + idx * 8),
            (__attribute__((address_space(3))) void*)(lds_w2 + idx * 8),
            16, 0, 0);
      }
    }
    __syncthreads();

    // per-row label / drop
    float xs[MT];
    #pragma unroll
    for (int mt = 0; mt < MT; ++mt){
      float x = lds_lab[d * BROWS + wave * 32 + mt * 16 + l16];
      bool drop = (uncond != 0) || (x != x);
      xs[mt] = drop ? 0.f : x;
    }

    // A fragments: t-outer so w1/b1 b128 loads are shared across both mt
    s16x8 af[MT][4];
    #pragma unroll
    for (int t = 0; t < 4; ++t){
      const float4* w1q = (const float4*)&lds_w1[d * NH + t * 32 + quad * 8];
      const float4* b1q = (const float4*)&lds_b1[d * NH + t * 32 + quad * 8];
      float4 wa = w1q[0], wb = w1q[1];
      float4 ba = b1q[0], bb = b1q[1];
      #pragma unroll
      for (int mt = 0; mt < MT; ++mt){
        float x = xs[mt];
        float e0 = EXP2F(fmaf(x, wa.x, ba.x));
        float e1 = EXP2F(fmaf(x, wa.y, ba.y));
        float e2 = EXP2F(fmaf(x, wa.z, ba.z));
        float e3 = EXP2F(fmaf(x, wa.w, ba.w));
        float e4 = EXP2F(fmaf(x, wb.x, bb.x));
        float e5 = EXP2F(fmaf(x, wb.y, bb.y));
        float e6 = EXP2F(fmaf(x, wb.z, bb.z));
        float e7 = EXP2F(fmaf(x, wb.w, bb.w));
        i32x4 ai;
        ai[0] = (int)pk2(e0, e1);
        ai[1] = (int)pk2(e2, e3);
        ai[2] = (int)pk2(e4, e5);
        ai[3] = (int)pk2(e6, e7);
        af[mt][t] = __builtin_bit_cast(s16x8, ai);
      }
    }

    // Z per row via ones-MFMA (sum of quantized e -> truncation cancels);
    // result lands in C layout, exactly where the scale-add needs it
    f32x4 zr[MT];
    #pragma unroll
    for (int mt = 0; mt < MT; ++mt){
      f32x4 z = (f32x4){0.f, 0.f, 0.f, 0.f};
      #pragma unroll
      for (int t = 0; t < 4; ++t)
        z = __builtin_amdgcn_mfma_f32_16x16x32_bf16(af[mt][t], bones, z, 0, 0, 0);
      float4 xc = *(const float4*)&lds_lab[d * BROWS + wave * 32 + mt * 16 + quad * 4];
      zr[mt][0] = ((uncond != 0) || (xc.x != xc.x)) ? 0.f : RCPF(z[0]);
      zr[mt][1] = ((uncond != 0) || (xc.y != xc.y)) ? 0.f : RCPF(z[1]);
      zr[mt][2] = ((uncond != 0) || (xc.z != xc.z)) ? 0.f : RCPF(z[2]);
      zr[mt][3] = ((uncond != 0) || (xc.w != xc.w)) ? 0.f : RCPF(z[3]);
    }

    // GEMM: per n-tile 4-step MFMA chains into temps, then scale-add by 1/Z
    #pragma unroll
    for (int nt = 0; nt < 8; ++nt){
      f32x4 t0 = (f32x4){0.f,0.f,0.f,0.f};
      f32x4 t1 = (f32x4){0.f,0.f,0.f,0.f};
      #pragma unroll
      for (int t = 0; t < 4; ++t){
        s16x8 b = *((const s16x8*)&lds_w2[(t * 512 + quad * 128 + nt * 16 + l16) * 8]);
        t0 = __builtin_amdgcn_mfma_f32_16x16x32_bf16(af[0][t], b, t0, 0, 0, 0);
        t1 = __builtin_amdgcn_mfma_f32_16x16x32_bf16(af[1][t], b, t1, 0, 0, 0);
      }
      #pragma unroll
      for (int r = 0; r < 4; ++r){
        acc[0][nt][r] = fmaf(t0[r], zr[0][r], acc[0][nt][r]);
        acc[1][nt][r] = fmaf(t1[r], zr[1][r], acc[1][nt][r]);
      }
    }
  }

  // Embedding fallback: A_extra[m][k=d] = drop?1:0 (quad 0), B_extra[k=d][n] = emb_w[d][n]
  s16x8 aex[MT];
  #pragma unroll
  for (int mt = 0; mt < MT; ++mt){
    s16x8 a = (s16x8)((short)0);
    if (quad == 0){
      int row = wave * 32 + mt * 16 + l16;
      #pragma unroll
      for (int j = 0; j < 8; ++j){
        float x = lds_lab[j * BROWS + row];
        bool drop = (uncond != 0) || (x != x);
        a[j] = drop ? (short)0x3F80 : (short)0;
      }
    }
    aex[mt] = a;
  }
  #pragma unroll
  for (int nt = 0; nt < 8; ++nt){
    s16x8 b = (s16x8)((short)0);
    if (quad == 0) b = __builtin_bit_cast(s16x8, ((const i32x4*)embT)[nt * 16 + l16]);
    #pragma unroll
    for (int mt = 0; mt < MT; ++mt)
      acc[mt][nt] = __builtin_amdgcn_mfma_f32_16x16x32_bf16(aex[mt], b, acc[mt][nt], 0, 0, 0);
  }

  // store: C layout col = l16, row = quad*4 + r
  #pragma unroll
  for (int mt = 0; mt < MT; ++mt){
    #pragma unroll
    for (int nt = 0; nt < 8; ++nt){
      #pragma unroll
      for (int r = 0; r < 4; ++r){
        int row = blockbase + wave * 32 + mt * 16 + quad * 4 + r;
        out[row * NH + nt * 16 + l16] = acc[mt][nt][r];
      }
    }
  }
}

extern "C" void kernel_launch(void* const* d_in, const int* in_sizes, int n_in,
                              void* d_out, int out_size, void* d_ws, size_t ws_size,
                              hipStream_t stream){
  const float* labels = (const float*)d_in[0];
  const float* emb_w  = (const float*)d_in[1];
  const float* w1     = (const float*)d_in[2];
  const float* b1     = (const float*)d_in[3];
  const float* w2     = (const float*)d_in[4];
  const int*   uncond = (const int*)d_in[6];
  (void)in_sizes; (void)n_in; (void)out_size; (void)ws_size;

  float* out = (float*)d_out;
  unsigned short* w2b  = (unsigned short*)d_ws;          // 256 KB bf16 w2
  unsigned short* embT = w2b + ND * NH * NH;             // +2 KB bf16 embT[n][8]

  cvt_w2_kernel<<<64, 256, 0, stream>>>(w2, (uint4*)w2b);
  cvt_emb_kernel<<<1, 128, 0, stream>>>(emb_w, (uint4*)embT);
  cond_embed_kernel<<<NB / BROWS, 256, 0, stream>>>(labels, w1, b1, w2b, embT, uncond, out);
}

// Round 5
// 131.430 us; speedup vs baseline: 1.2228x; 1.0406x over previous
//
#include <hip/hip_runtime.h>
#include <hip/hip_bf16.h>

typedef __attribute__((ext_vector_type(4))) float f32x4;
typedef __attribute__((ext_vector_type(4))) int   i32x4;
typedef __attribute__((ext_vector_type(8))) short s16x8;

#define NB 131072
#define ND 8
#define NH 128
#define BROWS 128   // rows per block
#define MT 2        // 16-row tiles per wave (register-lean: no spills)

#if __has_builtin(__builtin_amdgcn_exp2f)
#define EXP2F(x) __builtin_amdgcn_exp2f(x)
#define PRESCALE 1.4426950408889634f
#else
#define EXP2F(x) __expf(x)
#define PRESCALE 1.0f
#endif

#if __has_builtin(__builtin_amdgcn_rcpf)
#define RCPF(x) __builtin_amdgcn_rcpf(x)
#else
#define RCPF(x) (1.0f / (x))
#endif

__device__ __forceinline__ unsigned short f2bf(float f){
  unsigned u = __float_as_uint(f);
  u += 0x7fffu + ((u >> 16) & 1u);   // RTNE
  return (unsigned short)(u >> 16);
}

// pack two f32 -> dword of 2 bf16 (truncation), single v_perm_b32
__device__ __forceinline__ unsigned pk2(float lo, float hi){
  return __builtin_amdgcn_perm(__float_as_uint(hi), __float_as_uint(lo), 0x07060302u);
}

// w2 [d][n][k] f32 -> bf16 chunks [d][kb=k/8][n][8]
__global__ __launch_bounds__(256) void cvt_w2_kernel(const float* __restrict__ src,
                                                     uint4* __restrict__ dst){
  int i = blockIdx.x * 256 + threadIdx.x;         // 16384 chunks
  int d = i >> 11, kb = (i >> 7) & 15, n = i & 127;
  const float* s = src + ((d * 128 + n) * 128 + kb * 8);
  float4 v0 = ((const float4*)s)[0];
  float4 v1 = ((const float4*)s)[1];
  uint4 o;
  o.x = (unsigned)f2bf(v0.x) | ((unsigned)f2bf(v0.y) << 16);
  o.y = (unsigned)f2bf(v0.z) | ((unsigned)f2bf(v0.w) << 16);
  o.z = (unsigned)f2bf(v1.x) | ((unsigned)f2bf(v1.y) << 16);
  o.w = (unsigned)f2bf(v1.z) | ((unsigned)f2bf(v1.w) << 16);
  dst[i] = o;
}

// emb_w [d][n] f32 -> embT [n][8] bf16 (RTNE)
__global__ void cvt_emb_kernel(const float* __restrict__ emb_w, uint4* __restrict__ dst){
  int n = threadIdx.x;  // 128
  unsigned e0 = f2bf(emb_w[0*NH + n]), e1 = f2bf(emb_w[1*NH + n]);
  unsigned e2 = f2bf(emb_w[2*NH + n]), e3 = f2bf(emb_w[3*NH + n]);
  unsigned e4 = f2bf(emb_w[4*NH + n]), e5 = f2bf(emb_w[5*NH + n]);
  unsigned e6 = f2bf(emb_w[6*NH + n]), e7 = f2bf(emb_w[7*NH + n]);
  uint4 v;
  v.x = e0 | (e1 << 16);  v.y = e2 | (e3 << 16);
  v.z = e4 | (e5 << 16);  v.w = e6 | (e7 << 16);
  dst[n] = v;
}

__global__ __launch_bounds__(256, 2) void cond_embed_kernel(
    const float* __restrict__ labels,
    const float* __restrict__ w1,
    const float* __restrict__ b1,
    const unsigned short* __restrict__ w2b,   // [d][kb][n][8] bf16
    const unsigned short* __restrict__ embT,  // [n][8] bf16
    const int* __restrict__ uncond_p,
    float* __restrict__ out)
{
  __shared__ __align__(16) unsigned short lds_w2[2][NH * NH];  // 64 KB double buffer
  __shared__ __align__(16) float lds_lab[ND * BROWS];          // 4 KB, [d][row]
  __shared__ __align__(16) float lds_w1[ND * NH];              // 4 KB (log2e-scaled)
  __shared__ __align__(16) float lds_b1[ND * NH];              // 4 KB (log2e-scaled)
  // 76 KB total -> 2 blocks/CU

  const int tid  = threadIdx.x;
  const int wave = tid >> 6;
  const int lane = tid & 63;
  const int quad = lane >> 4;
  const int l16  = lane & 15;
  const int uncond = uncond_p[0];
  const int blockbase = blockIdx.x * BROWS;

  auto stage = [&](int d, int buf){
    const unsigned short* g = w2b + d * (NH * NH);
    #pragma unroll
    for (int i = 0; i < 8; ++i){
      int idx = tid + i * 256;   // 16B chunks, 2048 total = 32 KB
      __builtin_amdgcn_global_load_lds(
          (const __attribute__((address_space(1))) void*)(g + idx * 8),
          (__attribute__((address_space(3))) void*)(&lds_w2[buf][idx * 8]),
          16, 0, 0);
    }
  };

  // kick off d=0 staging first so it overlaps the other LDS prep
  stage(0, 0);

  // labels -> LDS transposed [d][row]
  {
    float4 v = ((const float4*)(labels + blockbase * ND))[tid];
    int row = tid >> 1, db = (tid & 1) * 4;
    lds_lab[(db + 0) * BROWS + row] = v.x;
    lds_lab[(db + 1) * BROWS + row] = v.y;
    lds_lab[(db + 2) * BROWS + row] = v.z;
    lds_lab[(db + 3) * BROWS + row] = v.w;
  }
  // w1/b1 pre-scaled by log2e
  {
    float4 a = ((const float4*)w1)[tid];
    float4 b = ((const float4*)b1)[tid];
    ((float4*)lds_w1)[tid] = (float4){a.x * PRESCALE, a.y * PRESCALE, a.z * PRESCALE, a.w * PRESCALE};
    ((float4*)lds_b1)[tid] = (float4){b.x * PRESCALE, b.y * PRESCALE, b.z * PRESCALE, b.w * PRESCALE};
  }

  f32x4 acc[MT][8];
  #pragma unroll
  for (int mt = 0; mt < MT; ++mt)
    #pragma unroll
    for (int nt = 0; nt < 8; ++nt)
      acc[mt][nt] = (f32x4){0.f, 0.f, 0.f, 0.f};

  const s16x8 bones = (s16x8)((short)0x3F80);   // bf16 1.0

  __syncthreads();   // drains stage(0) + label/w1/b1 staging

  for (int d = 0; d < ND; ++d){
    const int buf = d & 1;
    // prefetch next tile into the other buffer; has the whole compute
    // phase below to land before the end-of-iteration barrier drains it
    if (d < ND - 1) stage(d + 1, buf ^ 1);

    // per-row label / drop
    float xs[MT];
    #pragma unroll
    for (int mt = 0; mt < MT; ++mt){
      float x = lds_lab[d * BROWS + wave * 32 + mt * 16 + l16];
      bool drop = (uncond != 0) || (x != x);
      xs[mt] = drop ? 0.f : x;
    }

    // A fragments: t-outer so w1/b1 b128 loads are shared across both mt
    s16x8 af[MT][4];
    #pragma unroll
    for (int t = 0; t < 4; ++t){
      const float4* w1q = (const float4*)&lds_w1[d * NH + t * 32 + quad * 8];
      const float4* b1q = (const float4*)&lds_b1[d * NH + t * 32 + quad * 8];
      float4 wa = w1q[0], wb = w1q[1];
      float4 ba = b1q[0], bb = b1q[1];
      #pragma unroll
      for (int mt = 0; mt < MT; ++mt){
        float x = xs[mt];
        float e0 = EXP2F(fmaf(x, wa.x, ba.x));
        float e1 = EXP2F(fmaf(x, wa.y, ba.y));
        float e2 = EXP2F(fmaf(x, wa.z, ba.z));
        float e3 = EXP2F(fmaf(x, wa.w, ba.w));
        float e4 = EXP2F(fmaf(x, wb.x, bb.x));
        float e5 = EXP2F(fmaf(x, wb.y, bb.y));
        float e6 = EXP2F(fmaf(x, wb.z, bb.z));
        float e7 = EXP2F(fmaf(x, wb.w, bb.w));
        i32x4 ai;
        ai[0] = (int)pk2(e0, e1);
        ai[1] = (int)pk2(e2, e3);
        ai[2] = (int)pk2(e4, e5);
        ai[3] = (int)pk2(e6, e7);
        af[mt][t] = __builtin_bit_cast(s16x8, ai);
      }
    }

    // Z per row via ones-MFMA (sum of quantized e -> truncation cancels);
    // result lands in C layout, exactly where the scale-add needs it
    f32x4 zr[MT];
    #pragma unroll
    for (int mt = 0; mt < MT; ++mt){
      f32x4 z = (f32x4){0.f, 0.f, 0.f, 0.f};
      #pragma unroll
      for (int t = 0; t < 4; ++t)
        z = __builtin_amdgcn_mfma_f32_16x16x32_bf16(af[mt][t], bones, z, 0, 0, 0);
      float4 xc = *(const float4*)&lds_lab[d * BROWS + wave * 32 + mt * 16 + quad * 4];
      zr[mt][0] = ((uncond != 0) || (xc.x != xc.x)) ? 0.f : RCPF(z[0]);
      zr[mt][1] = ((uncond != 0) || (xc.y != xc.y)) ? 0.f : RCPF(z[1]);
      zr[mt][2] = ((uncond != 0) || (xc.z != xc.z)) ? 0.f : RCPF(z[2]);
      zr[mt][3] = ((uncond != 0) || (xc.w != xc.w)) ? 0.f : RCPF(z[3]);
    }

    // GEMM: per n-tile 4-step MFMA chains into temps, then scale-add by 1/Z
    #pragma unroll
    for (int nt = 0; nt < 8; ++nt){
      f32x4 t0 = (f32x4){0.f,0.f,0.f,0.f};
      f32x4 t1 = (f32x4){0.f,0.f,0.f,0.f};
      #pragma unroll
      for (int t = 0; t < 4; ++t){
        s16x8 b = *((const s16x8*)&lds_w2[buf][(t * 512 + quad * 128 + nt * 16 + l16) * 8]);
        t0 = __builtin_amdgcn_mfma_f32_16x16x32_bf16(af[0][t], b, t0, 0, 0, 0);
        t1 = __builtin_amdgcn_mfma_f32_16x16x32_bf16(af[1][t], b, t1, 0, 0, 0);
      }
      #pragma unroll
      for (int r = 0; r < 4; ++r){
        acc[0][nt][r] = fmaf(t0[r], zr[0][r], acc[0][nt][r]);
        acc[1][nt][r] = fmaf(t1[r], zr[1][r], acc[1][nt][r]);
      }
    }

    // one barrier per d: ensures stage(d+1) is drained (compiler emits the
    // vmcnt wait here) and no wave advances to stage(d+2) while buf is read
    if (d < ND - 1) __syncthreads();
  }

  // Embedding fallback: A_extra[m][k=d] = drop?1:0 (quad 0), B_extra[k=d][n] = emb_w[d][n]
  s16x8 aex[MT];
  #pragma unroll
  for (int mt = 0; mt < MT; ++mt){
    s16x8 a = (s16x8)((short)0);
    if (quad == 0){
      int row = wave * 32 + mt * 16 + l16;
      #pragma unroll
      for (int j = 0; j < 8; ++j){
        float x = lds_lab[j * BROWS + row];
        bool drop = (uncond != 0) || (x != x);
        a[j] = drop ? (short)0x3F80 : (short)0;
      }
    }
    aex[mt] = a;
  }
  #pragma unroll
  for (int nt = 0; nt < 8; ++nt){
    s16x8 b = (s16x8)((short)0);
    if (quad == 0) b = __builtin_bit_cast(s16x8, ((const i32x4*)embT)[nt * 16 + l16]);
    #pragma unroll
    for (int mt = 0; mt < MT; ++mt)
      acc[mt][nt] = __builtin_amdgcn_mfma_f32_16x16x32_bf16(aex[mt], b, acc[mt][nt], 0, 0, 0);
  }

  // store: C layout col = l16, row = quad*4 + r
  #pragma unroll
  for (int mt = 0; mt < MT; ++mt){
    #pragma unroll
    for (int nt = 0; nt < 8; ++nt){
      #pragma unroll
      for (int r = 0; r < 4; ++r){
        int row = blockbase + wave * 32 + mt * 16 + quad * 4 + r;
        out[row * NH + nt * 16 + l16] = acc[mt][nt][r];
      }
    }
  }
}

extern "C" void kernel_launch(void* const* d_in, const int* in_sizes, int n_in,
                              void* d_out, int out_size, void* d_ws, size_t ws_size,
                              hipStream_t stream){
  const float* labels = (const float*)d_in[0];
  const float* emb_w  = (const float*)d_in[1];
  const float* w1     = (const float*)d_in[2];
  const float* b1     = (const float*)d_in[3];
  const float* w2     = (const float*)d_in[4];
  const int*   uncond = (const int*)d_in[6];
  (void)in_sizes; (void)n_in; (void)out_size; (void)ws_size;

  float* out = (float*)d_out;
  unsigned short* w2b  = (unsigned short*)d_ws;          // 256 KB bf16 w2
  unsigned short* embT = w2b + ND * NH * NH;             // +2 KB bf16 embT[n][8]

  cvt_w2_kernel<<<64, 256, 0, stream>>>(w2, (uint4*)w2b);
  cvt_emb_kernel<<<1, 128, 0, stream>>>(emb_w, (uint4*)embT);
  cond_embed_kernel<<<NB / BROWS, 256, 0, stream>>>(labels, w1, b1, w2b, embT, uncond, out);
}